// Round 7
// baseline (1176.851 us; speedup 1.0000x reference)
//
#include <hip/hip_runtime.h>

#define MTOK 32768   // 8*4096 tokens
#define CIN  512     // in_ch
#define EMB  256     // emb_ch
#define NCODE 1024
#define VQ   3
#define DELTA 2e-3f  // certified margin; worst-case approx score-diff error ~3e-4

typedef short s16x8 __attribute__((ext_vector_type(8)));
typedef float f32x4 __attribute__((ext_vector_type(4)));
typedef unsigned short u16;

static __device__ __forceinline__ u16 f2bf(float x) {
    unsigned int u = __float_as_uint(x);
    u += 0x7FFF + ((u >> 16) & 1);          // RNE
    return (u16)(u >> 16);
}
static __device__ __forceinline__ float bf2f(u16 h) {
    return __uint_as_float(((unsigned int)h) << 16);
}

// ---------------- init ----------------
__global__ void init_k(double* loss_acc, int* cnt) {
    loss_acc[0] = 0.0;  // sum of min-dists (znorm parts + score parts)
    loss_acc[1] = 0.0;  // sum (z - z_q)^2
    cnt[0] = 0; cnt[1] = 0; cnt[2] = 0;
}

// ---------------- codebook prep: ||v||^2 (fp64/fp32) + bf16 hi/lo split ----------------
__global__ __launch_bounds__(64) void prep_cb_k(const float* __restrict__ cbs,
                                                double* __restrict__ vnorm64,
                                                float* __restrict__ vnorm32,
                                                u16* __restrict__ cbh,
                                                u16* __restrict__ cbl) {
    int s = blockIdx.x;                       // 0 .. 3*NCODE-1
    const float* row = cbs + (size_t)s * EMB;
    double acc = 0.0;
    for (int k = threadIdx.x; k < EMB; k += 64) {
        float v = row[k];
        double vd = (double)v; acc += vd * vd;
        u16 h = f2bf(v);
        u16 l = f2bf(v - bf2f(h));
        cbh[(size_t)s * EMB + k] = h;
        cbl[(size_t)s * EMB + k] = l;
    }
    #pragma unroll
    for (int off = 32; off > 0; off >>= 1) acc += __shfl_down(acc, off, 64);
    if (threadIdx.x == 0) { vnorm64[s] = acc; vnorm32[s] = (float)acc; }
}

// ---------------- W_in bf16 hi/lo split ----------------
__global__ __launch_bounds__(256) void prep_w_k(const float* __restrict__ W_in,
                                                u16* __restrict__ wh,
                                                u16* __restrict__ wl) {
    int i = blockIdx.x * 256 + threadIdx.x;   // < VQ*EMB*CIN
    float v = W_in[i];
    u16 h = f2bf(v);
    wh[i] = h;
    wl[i] = f2bf(v - bf2f(h));
}

// ---------------- T[s] = cb[s] @ W_out[s]^T  (fp64 acc, fp32 store) ----------------
__global__ __launch_bounds__(256) void prep_T_k(const float* __restrict__ cbs,
                                                const float* __restrict__ Wout,
                                                float* __restrict__ T) {
    const int stage = blockIdx.z;
    const float* A = cbs  + (size_t)stage * NCODE * EMB;
    const float* B = Wout + (size_t)stage * CIN * EMB;
    float* C = T + (size_t)stage * NCODE * CIN;
    __shared__ float As[64][33];
    __shared__ float Bs[64][33];
    const int tid = threadIdx.x;
    const int ty = tid >> 4, tx = tid & 15;
    const int m0 = blockIdx.x * 64;
    const int n0 = blockIdx.y * 64;
    const int lrow = tid >> 5, lcol = tid & 31;
    double acc[4][4];
    #pragma unroll
    for (int i = 0; i < 4; ++i)
        #pragma unroll
        for (int j = 0; j < 4; ++j) acc[i][j] = 0.0;

    for (int k0 = 0; k0 < EMB; k0 += 32) {
        __syncthreads();
        #pragma unroll
        for (int t = 0; t < 8; ++t) {
            int r = lrow + 8 * t;
            As[r][lcol] = A[(size_t)(m0 + r) * EMB + k0 + lcol];
            Bs[r][lcol] = B[(size_t)(n0 + r) * EMB + k0 + lcol];
        }
        __syncthreads();
        #pragma unroll
        for (int k = 0; k < 32; ++k) {
            double a[4], b[4];
            #pragma unroll
            for (int i = 0; i < 4; ++i) a[i] = (double)As[ty * 4 + i][k];
            #pragma unroll
            for (int j = 0; j < 4; ++j) b[j] = (double)Bs[tx * 4 + j][k];
            #pragma unroll
            for (int i = 0; i < 4; ++i)
                #pragma unroll
                for (int j = 0; j < 4; ++j) acc[i][j] += a[i] * b[j];
        }
    }
    #pragma unroll
    for (int i = 0; i < 4; ++i) {
        float4 v = make_float4((float)acc[i][0], (float)acc[i][1],
                               (float)acc[i][2], (float)acc[i][3]);
        *reinterpret_cast<float4*>(&C[(size_t)(m0 + ty * 4 + i) * CIN + n0 + tx * 4]) = v;
    }
}

// ---------------- zi = (z - zq) @ W_in^T via bf16-split MFMA, dbuf LDS W ----------------
__global__ __launch_bounds__(256, 2) void zi_mfma_k(const float* __restrict__ z,
                                                    const float* __restrict__ zq,
                                                    const u16* __restrict__ wh,
                                                    const u16* __restrict__ wl,
                                                    float* __restrict__ zi,
                                                    double* __restrict__ loss_acc,
                                                    int stage0) {
    __shared__ __align__(16) u16 swh[2][16][520];
    __shared__ __align__(16) u16 swl[2][16][520];
    const int tid = threadIdx.x;
    const int w = tid >> 6;
    const int l = tid & 63;
    const int col = l & 15;
    const int g = l >> 4;
    const int mw = blockIdx.x * 64 + w * 16;
    const int sr = tid >> 4, sq = tid & 15;

    // A fragments: bf16 hi/lo split of residual row (mw+col), k = kc*32 + g*8 + j
    s16x8 ah[16], al[16];
    {
        const float* zr = z  + (size_t)(mw + col) * CIN + g * 8;
        const float* qr = zq + (size_t)(mw + col) * CIN + g * 8;
        #pragma unroll
        for (int kc = 0; kc < 16; ++kc) {
            float4 f0 = *reinterpret_cast<const float4*>(zr + kc * 32);
            float4 f1 = *reinterpret_cast<const float4*>(zr + kc * 32 + 4);
            float f[8] = {f0.x, f0.y, f0.z, f0.w, f1.x, f1.y, f1.z, f1.w};
            if (!stage0) {
                float4 q0 = *reinterpret_cast<const float4*>(qr + kc * 32);
                float4 q1 = *reinterpret_cast<const float4*>(qr + kc * 32 + 4);
                f[0] -= q0.x; f[1] -= q0.y; f[2] -= q0.z; f[3] -= q0.w;
                f[4] -= q1.x; f[5] -= q1.y; f[6] -= q1.z; f[7] -= q1.w;
            }
            #pragma unroll
            for (int j = 0; j < 8; ++j) {
                u16 h = f2bf(f[j]);
                u16 lo = f2bf(f[j] - bf2f(h));
                ah[kc][j] = (short)h; al[kc][j] = (short)lo;
            }
        }
    }

    const u16* gh = wh + (size_t)sr * CIN + sq * 8;
    const u16* gl = wl + (size_t)sr * CIN + sq * 8;
    uint4 h0, h1, h2, h3, l0, l1, l2, l3;
#define ZLOAD(NT) do { const u16* th = gh + (size_t)(NT) * (16 * CIN);                \
    const u16* tl = gl + (size_t)(NT) * (16 * CIN);                                   \
    h0 = *(const uint4*)(th);        h1 = *(const uint4*)(th + 128);                  \
    h2 = *(const uint4*)(th + 256);  h3 = *(const uint4*)(th + 384);                  \
    l0 = *(const uint4*)(tl);        l1 = *(const uint4*)(tl + 128);                  \
    l2 = *(const uint4*)(tl + 256);  l3 = *(const uint4*)(tl + 384); } while (0)
#define ZWRITE(P) do {                                                                \
    *(uint4*)&swh[P][sr][sq * 8]       = h0;  *(uint4*)&swh[P][sr][sq * 8 + 128] = h1;\
    *(uint4*)&swh[P][sr][sq * 8 + 256] = h2;  *(uint4*)&swh[P][sr][sq * 8 + 384] = h3;\
    *(uint4*)&swl[P][sr][sq * 8]       = l0;  *(uint4*)&swl[P][sr][sq * 8 + 128] = l1;\
    *(uint4*)&swl[P][sr][sq * 8 + 256] = l2;  *(uint4*)&swl[P][sr][sq * 8 + 384] = l3;\
    } while (0)
    ZLOAD(0); ZWRITE(0); ZLOAD(1);

    double zn = 0.0;
    for (int nt = 0; nt < 16; ++nt) {
        __syncthreads();                         // buf[nt&1] ready; prev reads done
        const int p = nt & 1;
        if (nt + 1 < 16) ZWRITE((nt + 1) & 1);
        if (nt + 2 < 16) ZLOAD(nt + 2);
        f32x4 a0 = {0.f, 0.f, 0.f, 0.f};
        f32x4 a1 = {0.f, 0.f, 0.f, 0.f};
        f32x4 a2 = {0.f, 0.f, 0.f, 0.f};
        #pragma unroll
        for (int kc = 0; kc < 16; ++kc) {
            s16x8 Bh = *(const s16x8*)&swh[p][col][g * 8 + kc * 32];
            s16x8 Bl = *(const s16x8*)&swl[p][col][g * 8 + kc * 32];
            a0 = __builtin_amdgcn_mfma_f32_16x16x32_bf16(ah[kc], Bh, a0, 0, 0, 0);
            a1 = __builtin_amdgcn_mfma_f32_16x16x32_bf16(al[kc], Bh, a1, 0, 0, 0);
            a2 = __builtin_amdgcn_mfma_f32_16x16x32_bf16(ah[kc], Bl, a2, 0, 0, 0);
        }
        #pragma unroll
        for (int r = 0; r < 4; ++r) {
            float v = a0[r] + a1[r] + a2[r];
            zi[(size_t)(mw + g * 4 + r) * EMB + nt * 16 + col] = v;
            zn += (double)v * (double)v;
        }
    }
#undef ZLOAD
#undef ZWRITE
    #pragma unroll
    for (int off = 32; off > 0; off >>= 1) zn += __shfl_down(zn, off, 64);
    if (l == 0) atomicAdd(loss_acc, zn);
}

// ---------------- MFMA bf16-split prefilter, dbuf LDS, top-3 tracking ----------------
__global__ __launch_bounds__(256, 2) void pref_k(const float* __restrict__ zi,
                                                 const u16* __restrict__ cbh,
                                                 const u16* __restrict__ cbl,
                                                 const float* __restrict__ vnorm32,
                                                 int* __restrict__ idx,
                                                 int* __restrict__ idx_sum,
                                                 float* __restrict__ mind,
                                                 int* __restrict__ flagged,
                                                 int* __restrict__ cnt,
                                                 int* __restrict__ cand2,
                                                 double* __restrict__ loss_acc,
                                                 int stage0, int cumprod) {
    __shared__ __align__(16) u16 sbh[2][16][264];
    __shared__ __align__(16) u16 sbl[2][16][264];
    __shared__ double loss_s[16];
    const int tid = threadIdx.x;
    const int w = tid >> 6;
    const int l = tid & 63;
    const int col = l & 15;
    const int g = l >> 4;
    const int mw = blockIdx.x * 64 + w * 16;
    const int sr = tid >> 4, sq = tid & 15;

    s16x8 ah[8], al[8];
    {
        const float* zr = zi + (size_t)(mw + col) * EMB + g * 8;
        #pragma unroll
        for (int kc = 0; kc < 8; ++kc) {
            float4 f0 = *reinterpret_cast<const float4*>(zr + kc * 32);
            float4 f1 = *reinterpret_cast<const float4*>(zr + kc * 32 + 4);
            float f[8] = {f0.x, f0.y, f0.z, f0.w, f1.x, f1.y, f1.z, f1.w};
            #pragma unroll
            for (int j = 0; j < 8; ++j) {
                u16 h = f2bf(f[j]);
                u16 lo = f2bf(f[j] - bf2f(h));
                ah[kc][j] = (short)h;
                al[kc][j] = (short)lo;
            }
        }
    }

    float b1[4] = {1e30f, 1e30f, 1e30f, 1e30f};
    float b2[4] = {1e30f, 1e30f, 1e30f, 1e30f};
    float b3[4] = {1e30f, 1e30f, 1e30f, 1e30f};
    int   i1[4] = {0, 0, 0, 0};
    int   i2[4] = {0, 0, 0, 0};

    const u16* gh = cbh + (size_t)sr * EMB + sq * 8;
    const u16* gl = cbl + (size_t)sr * EMB + sq * 8;
    uint4 h0, h1, l0, l1;
#define PLOAD(CT) do { const u16* th = gh + (size_t)(CT) * (16 * EMB);                \
    const u16* tl = gl + (size_t)(CT) * (16 * EMB);                                   \
    h0 = *(const uint4*)(th);  h1 = *(const uint4*)(th + 128);                        \
    l0 = *(const uint4*)(tl);  l1 = *(const uint4*)(tl + 128); } while (0)
#define PWRITE(P) do {                                                                \
    *(uint4*)&sbh[P][sr][sq * 8] = h0;  *(uint4*)&sbh[P][sr][sq * 8 + 128] = h1;      \
    *(uint4*)&sbl[P][sr][sq * 8] = l0;  *(uint4*)&sbl[P][sr][sq * 8 + 128] = l1;      \
    } while (0)
    PLOAD(0); PWRITE(0); PLOAD(1);

    for (int ct = 0; ct < 64; ++ct) {
        __syncthreads();                         // buf[ct&1] ready; prev reads done
        const int p = ct & 1;
        if (ct + 1 < 64) PWRITE((ct + 1) & 1);
        if (ct + 2 < 64) PLOAD(ct + 2);
        const float vn = vnorm32[ct * 16 + col];
        f32x4 a0 = {0.f, 0.f, 0.f, 0.f};
        f32x4 a1 = {0.f, 0.f, 0.f, 0.f};
        f32x4 a2 = {0.f, 0.f, 0.f, 0.f};
        #pragma unroll
        for (int kc = 0; kc < 8; ++kc) {
            s16x8 Bh = *(const s16x8*)&sbh[p][col][g * 8 + kc * 32];
            s16x8 Bl = *(const s16x8*)&sbl[p][col][g * 8 + kc * 32];
            a0 = __builtin_amdgcn_mfma_f32_16x16x32_bf16(ah[kc], Bh, a0, 0, 0, 0);
            a1 = __builtin_amdgcn_mfma_f32_16x16x32_bf16(al[kc], Bh, a1, 0, 0, 0);
            a2 = __builtin_amdgcn_mfma_f32_16x16x32_bf16(ah[kc], Bl, a2, 0, 0, 0);
        }
        #pragma unroll
        for (int r = 0; r < 4; ++r) {
            float sc = vn - 2.f * (a0[r] + a1[r] + a2[r]);
            int c = ct * 16 + col;
            if (sc < b1[r]) { b3[r] = b2[r]; b2[r] = b1[r]; i2[r] = i1[r]; b1[r] = sc; i1[r] = c; }
            else if (sc < b2[r]) { b3[r] = b2[r]; b2[r] = sc; i2[r] = c; }
            else b3[r] = fminf(b3[r], sc);
        }
    }
#undef PLOAD
#undef PWRITE

    // cross-lane top-3 merge over the 16 lanes of each token group
    #pragma unroll
    for (int off = 1; off < 16; off <<= 1) {
        #pragma unroll
        for (int r = 0; r < 4; ++r) {
            float c1 = __shfl_xor(b1[r], off, 64);
            int   j1 = __shfl_xor(i1[r], off, 64);
            float c2 = __shfl_xor(b2[r], off, 64);
            int   j2 = __shfl_xor(i2[r], off, 64);
            float c3 = __shfl_xor(b3[r], off, 64);
            float nb1, nb2, nb3; int ni1, ni2;
            if (c1 < b1[r] || (c1 == b1[r] && j1 < i1[r])) {
                nb1 = c1; ni1 = j1;
                if (b1[r] < c2 || (b1[r] == c2 && i1[r] < j2)) {
                    nb2 = b1[r]; ni2 = i1[r]; nb3 = fminf(b2[r], c2);
                } else {
                    nb2 = c2; ni2 = j2; nb3 = fminf(b1[r], c3);
                }
            } else {
                nb1 = b1[r]; ni1 = i1[r];
                if (c1 < b2[r] || (c1 == b2[r] && j1 < i2[r])) {
                    nb2 = c1; ni2 = j1; nb3 = fminf(b2[r], c2);
                } else {
                    nb2 = b2[r]; ni2 = i2[r]; nb3 = fminf(c1, b3[r]);
                }
            }
            b1[r] = nb1; b2[r] = nb2; b3[r] = nb3; i1[r] = ni1; i2[r] = ni2;
        }
    }
    if (col == 0) {
        double lsum = 0.0;
        #pragma unroll
        for (int r = 0; r < 4; ++r) {
            int m = mw + g * 4 + r;
            idx[m] = i1[r];
            if (stage0) idx_sum[m] = i1[r];
            else        idx_sum[m] += i1[r] * cumprod;
            mind[m] = b1[r];                 // score-only part
            lsum += (double)b1[r];
            if (b2[r] - b1[r] < DELTA) {
                int slot = atomicAdd(cnt, 1);
                int full = (b3[r] - b1[r] < DELTA) ? 1 : 0;
                flagged[slot] = (m << 1) | full;
                cand2[m] = i2[r];
            }
        }
        loss_s[w * 4 + g] = lsum;
    }
    __syncthreads();
    if (tid == 0) {
        double s = 0.0;
        #pragma unroll
        for (int q = 0; q < 16; ++q) s += loss_s[q];
        atomicAdd(loss_acc, s);
    }
}

// ---------------- exact fp64 rescan, coalesced; pair-mode or full-scan ----------------
__global__ __launch_bounds__(256) void rescan_k(const float* __restrict__ z,
                                                const float* __restrict__ zqv,
                                                const float* __restrict__ Win,
                                                const float* __restrict__ cb,
                                                const double* __restrict__ vnorm64,
                                                const int* __restrict__ flagged,
                                                const int* __restrict__ cnt,
                                                const int* __restrict__ cand2,
                                                int* __restrict__ idx,
                                                int* __restrict__ idx_sum,
                                                float* __restrict__ mind,
                                                double* __restrict__ loss_acc,
                                                int cumprod, int stage0) {
    __shared__ double zi64[EMB];
    __shared__ double sred[4];
    __shared__ int ired[4];
    const int tid = threadIdx.x;
    const int w = tid >> 6, l = tid & 63;
    int n = *cnt;
    for (int j = blockIdx.x; j < n; j += gridDim.x) {
        int fm = flagged[j];
        int m = fm >> 1;
        int full = fm & 1;
        __syncthreads();                      // protect zi64/sred reuse across j
        // per-lane residual slice: rr[jj] = r[l + 64*jj]  (coalesced)
        double rr[8];
        {
            const float* zr = z   + (size_t)m * CIN + l;
            const float* qr = zqv + (size_t)m * CIN + l;
            #pragma unroll
            for (int jj = 0; jj < 8; ++jj) {
                float rv = zr[64 * jj];
                if (!stage0) rv -= qr[64 * jj];   // fp32 subtract (matches ref)
                rr[jj] = (double)rv;
            }
        }
        // zi64[e] (fp64): wave w computes e = 64w+eo; full W row read coalesced
        for (int eo = 0; eo < 64; ++eo) {
            int e = (w << 6) + eo;
            const float* wr = Win + (size_t)e * CIN + l;
            double s = 0.0;
            #pragma unroll
            for (int jj = 0; jj < 8; ++jj) s += rr[jj] * (double)wr[64 * jj];
            #pragma unroll
            for (int off = 1; off < 64; off <<= 1) s += __shfl_xor(s, off, 64);
            if (l == 0) zi64[e] = s;
        }
        __syncthreads();
        double z0 = zi64[4 * l], z1 = zi64[4 * l + 1];
        double z2 = zi64[4 * l + 2], z3 = zi64[4 * l + 3];
        if (full) {
            double best = 1e300; int bi = 0;
            for (int c = w; c < NCODE; c += 4) {
                float4 v = *(const float4*)(cb + (size_t)c * EMB + 4 * l);
                double s = z0 * (double)v.x + z1 * (double)v.y
                         + z2 * (double)v.z + z3 * (double)v.w;
                #pragma unroll
                for (int off = 1; off < 64; off <<= 1) s += __shfl_xor(s, off, 64);
                double sc = vnorm64[c] - 2.0 * s;
                if (sc < best) { best = sc; bi = c; }    // ascending c: first-min
            }
            if (l == 0) { sred[w] = best; ired[w] = bi; }
            __syncthreads();
            if (tid == 0) {
                best = sred[0]; bi = ired[0];
                for (int q = 1; q < 4; ++q)
                    if (sred[q] < best || (sred[q] == best && ired[q] < bi)) {
                        best = sred[q]; bi = ired[q];
                    }
                int oldI = idx[m];
                if (bi != oldI) { idx[m] = bi; idx_sum[m] += (bi - oldI) * cumprod; }
                atomicAdd(loss_acc, best - (double)mind[m]);
                mind[m] = (float)best;
            }
        } else {
            int cA = idx[m];
            int cB = cand2[m];
            float4 vA = *(const float4*)(cb + (size_t)cA * EMB + 4 * l);
            float4 vB = *(const float4*)(cb + (size_t)cB * EMB + 4 * l);
            double sA = z0 * (double)vA.x + z1 * (double)vA.y
                      + z2 * (double)vA.z + z3 * (double)vA.w;
            double sB = z0 * (double)vB.x + z1 * (double)vB.y
                      + z2 * (double)vB.z + z3 * (double)vB.w;
            #pragma unroll
            for (int off = 1; off < 64; off <<= 1) {
                sA += __shfl_xor(sA, off, 64);
                sB += __shfl_xor(sB, off, 64);
            }
            if (tid == 0) {
                double dA = vnorm64[cA] - 2.0 * sA;
                double dB = vnorm64[cB] - 2.0 * sB;
                int bi; double best;
                if (dB < dA || (dB == dA && cB < cA)) { bi = cB; best = dB; }
                else                                   { bi = cA; best = dA; }
                int oldI = idx[m];
                if (bi != oldI) { idx[m] = bi; idx_sum[m] += (bi - oldI) * cumprod; }
                atomicAdd(loss_acc, best - (double)mind[m]);
                mind[m] = (float)best;
            }
        }
    }
}

// ---------------- zq (+)= T[idx]  (row gather); last stage also sums (z - zq)^2 ----------------
__global__ __launch_bounds__(256) void gather_k(const float* __restrict__ T,
                                                const int* __restrict__ idx,
                                                const float* __restrict__ z,
                                                float* __restrict__ zq,
                                                int stage0, int last,
                                                double* __restrict__ loss_acc) {
    __shared__ double red[256];
    int m = blockIdx.x * 16 + (threadIdx.x >> 4);
    int q = threadIdx.x & 15;
    const float* src = T + (size_t)idx[m] * CIN;
    float* dst = zq + (size_t)m * CIN;
    double s = 0.0;
    #pragma unroll
    for (int it = 0; it < 8; ++it) {
        int off = it * 64 + q * 4;
        float4 t = *reinterpret_cast<const float4*>(src + off);
        if (!stage0) {
            float4 o = *reinterpret_cast<const float4*>(dst + off);
            t.x += o.x; t.y += o.y; t.z += o.z; t.w += o.w;
        }
        *reinterpret_cast<float4*>(dst + off) = t;
        if (last) {
            float4 zv = *reinterpret_cast<const float4*>(z + (size_t)m * CIN + off);
            double d0 = (double)zv.x - (double)t.x;
            double d1 = (double)zv.y - (double)t.y;
            double d2 = (double)zv.z - (double)t.z;
            double d3 = (double)zv.w - (double)t.w;
            s += d0 * d0 + d1 * d1 + d2 * d2 + d3 * d3;
        }
    }
    if (last) {
        red[threadIdx.x] = s;
        __syncthreads();
        for (int off = 128; off > 0; off >>= 1) {
            if (threadIdx.x < off) red[threadIdx.x] += red[threadIdx.x + off];
            __syncthreads();
        }
        if (threadIdx.x == 0) atomicAdd(loss_acc + 1, red[0]);
    }
}

// ---------------- finalize ----------------
__global__ void final_k(const int* __restrict__ idx_sum,
                        const double* __restrict__ loss_acc,
                        float* __restrict__ out) {
    int i = blockIdx.x * blockDim.x + threadIdx.x;
    if (i < MTOK) out[MTOK * CIN + i] = (float)idx_sum[i];
    if (i == 0) {
        double loss = 2.0 * loss_acc[0] / (3.0 * (double)MTOK * (double)EMB)
                    + loss_acc[1] / ((double)MTOK * (double)CIN);
        out[MTOK * CIN + MTOK] = (float)loss;
    }
}

extern "C" void kernel_launch(void* const* d_in, const int* in_sizes, int n_in,
                              void* d_out, int out_size, void* d_ws, size_t ws_size,
                              hipStream_t stream) {
    const float* z     = (const float*)d_in[0];
    const float* W_in  = (const float*)d_in[1];
    const float* W_out = (const float*)d_in[2];
    const float* cbs   = (const float*)d_in[3];
    float* out = (float*)d_out;
    char* ws = (char*)d_ws;

    // ws layout (16B-aligned)
    double* vnorm64  = (double*)ws;                               // 24576
    double* loss_acc = (double*)(ws + 24576);                     // 16
    float*  vnorm32  = (float*)(ws + 24592);                      // 12288
    int*    cnt      = (int*)(ws + 36880);                        // 16
    u16*    cbh      = (u16*)(ws + 36896);                        // 1572864
    u16*    cbl      = (u16*)(ws + 1609760);                      // 1572864
    u16*    wh       = (u16*)(ws + 3182624);                      // 786432
    u16*    wl       = (u16*)(ws + 3969056);                      // 786432
    float*  T        = (float*)(ws + 4755488);                    // 6291456
    float*  zi       = (float*)(ws + 11046944);                   // 33554432
    char*   p        = ws + 11046944 + (size_t)MTOK * EMB * 4;
    int*    idx      = (int*)p;                                   // 131072
    int*    idx_sum  = (int*)(p + 131072);                        // 131072
    int*    flagged  = (int*)(p + 262144);                        // 131072
    float*  mind     = (float*)(p + 393216);                      // 131072
    int*    cand2    = (int*)(p + 524288);                        // 131072

    float* zq = out;  // z_q lives in d_out[0 .. MTOK*CIN)

    init_k<<<dim3(1), dim3(1), 0, stream>>>(loss_acc, cnt);
    prep_cb_k<<<dim3(VQ * NCODE), dim3(64), 0, stream>>>(cbs, vnorm64, vnorm32, cbh, cbl);
    prep_w_k<<<dim3(VQ * EMB * CIN / 256), dim3(256), 0, stream>>>(W_in, wh, wl);
    prep_T_k<<<dim3(NCODE / 64, CIN / 64, VQ), dim3(256), 0, stream>>>(cbs, W_out, T);

    const int cumprod[VQ] = {1, 1024, 1024 * 1024};
    for (int i = 0; i < VQ; ++i) {
        const float* cb = cbs + (size_t)i * NCODE * EMB;
        zi_mfma_k<<<dim3(MTOK / 64), dim3(256), 0, stream>>>(
            z, zq, wh + (size_t)i * EMB * CIN, wl + (size_t)i * EMB * CIN,
            zi, loss_acc, i == 0 ? 1 : 0);
        pref_k<<<dim3(MTOK / 64), dim3(256), 0, stream>>>(
            zi, cbh + (size_t)i * NCODE * EMB, cbl + (size_t)i * NCODE * EMB,
            vnorm32 + i * NCODE, idx, idx_sum, mind, flagged, cnt + i, cand2,
            loss_acc, i == 0 ? 1 : 0, cumprod[i]);
        rescan_k<<<dim3(512), dim3(256), 0, stream>>>(
            z, zq, W_in + (size_t)i * EMB * CIN, cb, vnorm64 + i * NCODE,
            flagged, cnt + i, cand2, idx, idx_sum, mind, loss_acc, cumprod[i],
            i == 0 ? 1 : 0);
        gather_k<<<dim3(MTOK / 16), dim3(256), 0, stream>>>(
            T + (size_t)i * NCODE * CIN, idx, z, zq, i == 0 ? 1 : 0,
            i == VQ - 1 ? 1 : 0, loss_acc);
    }
    final_k<<<dim3(MTOK / 256), dim3(256), 0, stream>>>(idx_sum, loss_acc, out);
}

// Round 8
// 930.403 us; speedup vs baseline: 1.2649x; 1.2649x over previous
//
#include <hip/hip_runtime.h>

#define MTOK 32768   // 8*4096 tokens
#define CIN  512     // in_ch
#define EMB  256     // emb_ch
#define NCODE 1024
#define VQ   3
#define DELTA 2e-3f  // certified margin; worst-case approx score-diff error ~3e-4

typedef short s16x8 __attribute__((ext_vector_type(8)));
typedef float f32x4 __attribute__((ext_vector_type(4)));
typedef unsigned short u16;

static __device__ __forceinline__ u16 f2bf(float x) {
    unsigned int u = __float_as_uint(x);
    u += 0x7FFF + ((u >> 16) & 1);          // RNE
    return (u16)(u >> 16);
}
static __device__ __forceinline__ float bf2f(u16 h) {
    return __uint_as_float(((unsigned int)h) << 16);
}

// ---------------- init ----------------
__global__ void init_k(double* loss_acc, int* cnt) {
    loss_acc[0] = 0.0;  // sum of min-dists (znorm parts + score parts)
    loss_acc[1] = 0.0;  // sum (z - z_q)^2
    cnt[0] = 0; cnt[1] = 0; cnt[2] = 0;
}

// ---------------- codebook prep: ||v||^2 (fp64/fp32) + bf16 hi/lo split ----------------
__global__ __launch_bounds__(64) void prep_cb_k(const float* __restrict__ cbs,
                                                double* __restrict__ vnorm64,
                                                float* __restrict__ vnorm32,
                                                u16* __restrict__ cbh,
                                                u16* __restrict__ cbl) {
    int s = blockIdx.x;                       // 0 .. 3*NCODE-1
    const float* row = cbs + (size_t)s * EMB;
    double acc = 0.0;
    for (int k = threadIdx.x; k < EMB; k += 64) {
        float v = row[k];
        double vd = (double)v; acc += vd * vd;
        u16 h = f2bf(v);
        u16 l = f2bf(v - bf2f(h));
        cbh[(size_t)s * EMB + k] = h;
        cbl[(size_t)s * EMB + k] = l;
    }
    #pragma unroll
    for (int off = 32; off > 0; off >>= 1) acc += __shfl_down(acc, off, 64);
    if (threadIdx.x == 0) { vnorm64[s] = acc; vnorm32[s] = (float)acc; }
}

// ---------------- W_in bf16 hi/lo split ----------------
__global__ __launch_bounds__(256) void prep_w_k(const float* __restrict__ W_in,
                                                u16* __restrict__ wh,
                                                u16* __restrict__ wl) {
    int i = blockIdx.x * 256 + threadIdx.x;   // < VQ*EMB*CIN
    float v = W_in[i];
    u16 h = f2bf(v);
    wh[i] = h;
    wl[i] = f2bf(v - bf2f(h));
}

// ---------------- W_in transpose: WinT[s][k][e] = W_in[s][e][k] (exact fp32) ----------------
__global__ __launch_bounds__(256) void prep_wt_k(const float* __restrict__ W_in,
                                                 float* __restrict__ WinT) {
    int i = blockIdx.x * 256 + threadIdx.x;   // < VQ*EMB*CIN
    int s = i / (EMB * CIN);
    int rem = i - s * (EMB * CIN);
    int e = rem / CIN;
    int k = rem - e * CIN;
    WinT[(size_t)s * CIN * EMB + (size_t)k * EMB + e] = W_in[i];
}

// ---------------- T[s] = cb[s] @ W_out[s]^T  (fp64 acc, fp32 store) ----------------
__global__ __launch_bounds__(256) void prep_T_k(const float* __restrict__ cbs,
                                                const float* __restrict__ Wout,
                                                float* __restrict__ T) {
    const int stage = blockIdx.z;
    const float* A = cbs  + (size_t)stage * NCODE * EMB;
    const float* B = Wout + (size_t)stage * CIN * EMB;
    float* C = T + (size_t)stage * NCODE * CIN;
    __shared__ float As[64][33];
    __shared__ float Bs[64][33];
    const int tid = threadIdx.x;
    const int ty = tid >> 4, tx = tid & 15;
    const int m0 = blockIdx.x * 64;
    const int n0 = blockIdx.y * 64;
    const int lrow = tid >> 5, lcol = tid & 31;
    double acc[4][4];
    #pragma unroll
    for (int i = 0; i < 4; ++i)
        #pragma unroll
        for (int j = 0; j < 4; ++j) acc[i][j] = 0.0;

    for (int k0 = 0; k0 < EMB; k0 += 32) {
        __syncthreads();
        #pragma unroll
        for (int t = 0; t < 8; ++t) {
            int r = lrow + 8 * t;
            As[r][lcol] = A[(size_t)(m0 + r) * EMB + k0 + lcol];
            Bs[r][lcol] = B[(size_t)(n0 + r) * EMB + k0 + lcol];
        }
        __syncthreads();
        #pragma unroll
        for (int k = 0; k < 32; ++k) {
            double a[4], b[4];
            #pragma unroll
            for (int i = 0; i < 4; ++i) a[i] = (double)As[ty * 4 + i][k];
            #pragma unroll
            for (int j = 0; j < 4; ++j) b[j] = (double)Bs[tx * 4 + j][k];
            #pragma unroll
            for (int i = 0; i < 4; ++i)
                #pragma unroll
                for (int j = 0; j < 4; ++j) acc[i][j] += a[i] * b[j];
        }
    }
    #pragma unroll
    for (int i = 0; i < 4; ++i) {
        float4 v = make_float4((float)acc[i][0], (float)acc[i][1],
                               (float)acc[i][2], (float)acc[i][3]);
        *reinterpret_cast<float4*>(&C[(size_t)(m0 + ty * 4 + i) * CIN + n0 + tx * 4]) = v;
    }
}

// ---------------- zi = (z - zq) @ W_in^T via bf16-split MFMA, dbuf LDS W ----------------
__global__ __launch_bounds__(256, 2) void zi_mfma_k(const float* __restrict__ z,
                                                    const float* __restrict__ zq,
                                                    const u16* __restrict__ wh,
                                                    const u16* __restrict__ wl,
                                                    float* __restrict__ zi,
                                                    double* __restrict__ loss_acc,
                                                    int stage0) {
    __shared__ __align__(16) u16 swh[2][16][520];
    __shared__ __align__(16) u16 swl[2][16][520];
    const int tid = threadIdx.x;
    const int w = tid >> 6;
    const int l = tid & 63;
    const int col = l & 15;
    const int g = l >> 4;
    const int mw = blockIdx.x * 64 + w * 16;
    const int sr = tid >> 4, sq = tid & 15;

    // A fragments: bf16 hi/lo split of residual row (mw+col), k = kc*32 + g*8 + j
    s16x8 ah[16], al[16];
    {
        const float* zr = z  + (size_t)(mw + col) * CIN + g * 8;
        const float* qr = zq + (size_t)(mw + col) * CIN + g * 8;
        #pragma unroll
        for (int kc = 0; kc < 16; ++kc) {
            float4 f0 = *reinterpret_cast<const float4*>(zr + kc * 32);
            float4 f1 = *reinterpret_cast<const float4*>(zr + kc * 32 + 4);
            float f[8] = {f0.x, f0.y, f0.z, f0.w, f1.x, f1.y, f1.z, f1.w};
            if (!stage0) {
                float4 q0 = *reinterpret_cast<const float4*>(qr + kc * 32);
                float4 q1 = *reinterpret_cast<const float4*>(qr + kc * 32 + 4);
                f[0] -= q0.x; f[1] -= q0.y; f[2] -= q0.z; f[3] -= q0.w;
                f[4] -= q1.x; f[5] -= q1.y; f[6] -= q1.z; f[7] -= q1.w;
            }
            #pragma unroll
            for (int j = 0; j < 8; ++j) {
                u16 h = f2bf(f[j]);
                u16 lo = f2bf(f[j] - bf2f(h));
                ah[kc][j] = (short)h; al[kc][j] = (short)lo;
            }
        }
    }

    const u16* gh = wh + (size_t)sr * CIN + sq * 8;
    const u16* gl = wl + (size_t)sr * CIN + sq * 8;
    uint4 h0, h1, h2, h3, l0, l1, l2, l3;
#define ZLOAD(NT) do { const u16* th = gh + (size_t)(NT) * (16 * CIN);                \
    const u16* tl = gl + (size_t)(NT) * (16 * CIN);                                   \
    h0 = *(const uint4*)(th);        h1 = *(const uint4*)(th + 128);                  \
    h2 = *(const uint4*)(th + 256);  h3 = *(const uint4*)(th + 384);                  \
    l0 = *(const uint4*)(tl);        l1 = *(const uint4*)(tl + 128);                  \
    l2 = *(const uint4*)(tl + 256);  l3 = *(const uint4*)(tl + 384); } while (0)
#define ZWRITE(P) do {                                                                \
    *(uint4*)&swh[P][sr][sq * 8]       = h0;  *(uint4*)&swh[P][sr][sq * 8 + 128] = h1;\
    *(uint4*)&swh[P][sr][sq * 8 + 256] = h2;  *(uint4*)&swh[P][sr][sq * 8 + 384] = h3;\
    *(uint4*)&swl[P][sr][sq * 8]       = l0;  *(uint4*)&swl[P][sr][sq * 8 + 128] = l1;\
    *(uint4*)&swl[P][sr][sq * 8 + 256] = l2;  *(uint4*)&swl[P][sr][sq * 8 + 384] = l3;\
    } while (0)
    ZLOAD(0); ZWRITE(0); ZLOAD(1);

    double zn = 0.0;
    for (int nt = 0; nt < 16; ++nt) {
        __syncthreads();                         // buf[nt&1] ready; prev reads done
        const int p = nt & 1;
        if (nt + 1 < 16) ZWRITE((nt + 1) & 1);
        if (nt + 2 < 16) ZLOAD(nt + 2);
        f32x4 a0 = {0.f, 0.f, 0.f, 0.f};
        f32x4 a1 = {0.f, 0.f, 0.f, 0.f};
        f32x4 a2 = {0.f, 0.f, 0.f, 0.f};
        #pragma unroll
        for (int kc = 0; kc < 16; ++kc) {
            s16x8 Bh = *(const s16x8*)&swh[p][col][g * 8 + kc * 32];
            s16x8 Bl = *(const s16x8*)&swl[p][col][g * 8 + kc * 32];
            a0 = __builtin_amdgcn_mfma_f32_16x16x32_bf16(ah[kc], Bh, a0, 0, 0, 0);
            a1 = __builtin_amdgcn_mfma_f32_16x16x32_bf16(al[kc], Bh, a1, 0, 0, 0);
            a2 = __builtin_amdgcn_mfma_f32_16x16x32_bf16(ah[kc], Bl, a2, 0, 0, 0);
        }
        #pragma unroll
        for (int r = 0; r < 4; ++r) {
            float v = a0[r] + a1[r] + a2[r];
            zi[(size_t)(mw + g * 4 + r) * EMB + nt * 16 + col] = v;
            zn += (double)v * (double)v;
        }
    }
#undef ZLOAD
#undef ZWRITE
    #pragma unroll
    for (int off = 32; off > 0; off >>= 1) zn += __shfl_down(zn, off, 64);
    if (l == 0) atomicAdd(loss_acc, zn);
}

// ---------------- MFMA bf16-split prefilter, dbuf LDS, top-3 tracking ----------------
__global__ __launch_bounds__(256, 2) void pref_k(const float* __restrict__ zi,
                                                 const u16* __restrict__ cbh,
                                                 const u16* __restrict__ cbl,
                                                 const float* __restrict__ vnorm32,
                                                 int* __restrict__ idx,
                                                 int* __restrict__ idx_sum,
                                                 float* __restrict__ mind,
                                                 int* __restrict__ flagged,
                                                 int* __restrict__ cnt,
                                                 int* __restrict__ cand2,
                                                 double* __restrict__ loss_acc,
                                                 int stage0, int cumprod) {
    __shared__ __align__(16) u16 sbh[2][16][264];
    __shared__ __align__(16) u16 sbl[2][16][264];
    __shared__ double loss_s[16];
    const int tid = threadIdx.x;
    const int w = tid >> 6;
    const int l = tid & 63;
    const int col = l & 15;
    const int g = l >> 4;
    const int mw = blockIdx.x * 64 + w * 16;
    const int sr = tid >> 4, sq = tid & 15;

    s16x8 ah[8], al[8];
    {
        const float* zr = zi + (size_t)(mw + col) * EMB + g * 8;
        #pragma unroll
        for (int kc = 0; kc < 8; ++kc) {
            float4 f0 = *reinterpret_cast<const float4*>(zr + kc * 32);
            float4 f1 = *reinterpret_cast<const float4*>(zr + kc * 32 + 4);
            float f[8] = {f0.x, f0.y, f0.z, f0.w, f1.x, f1.y, f1.z, f1.w};
            #pragma unroll
            for (int j = 0; j < 8; ++j) {
                u16 h = f2bf(f[j]);
                u16 lo = f2bf(f[j] - bf2f(h));
                ah[kc][j] = (short)h;
                al[kc][j] = (short)lo;
            }
        }
    }

    float b1[4] = {1e30f, 1e30f, 1e30f, 1e30f};
    float b2[4] = {1e30f, 1e30f, 1e30f, 1e30f};
    float b3[4] = {1e30f, 1e30f, 1e30f, 1e30f};
    int   i1[4] = {0, 0, 0, 0};
    int   i2[4] = {0, 0, 0, 0};

    const u16* gh = cbh + (size_t)sr * EMB + sq * 8;
    const u16* gl = cbl + (size_t)sr * EMB + sq * 8;
    uint4 h0, h1, l0, l1;
#define PLOAD(CT) do { const u16* th = gh + (size_t)(CT) * (16 * EMB);                \
    const u16* tl = gl + (size_t)(CT) * (16 * EMB);                                   \
    h0 = *(const uint4*)(th);  h1 = *(const uint4*)(th + 128);                        \
    l0 = *(const uint4*)(tl);  l1 = *(const uint4*)(tl + 128); } while (0)
#define PWRITE(P) do {                                                                \
    *(uint4*)&sbh[P][sr][sq * 8] = h0;  *(uint4*)&sbh[P][sr][sq * 8 + 128] = h1;      \
    *(uint4*)&sbl[P][sr][sq * 8] = l0;  *(uint4*)&sbl[P][sr][sq * 8 + 128] = l1;      \
    } while (0)
    PLOAD(0); PWRITE(0); PLOAD(1);

    for (int ct = 0; ct < 64; ++ct) {
        __syncthreads();                         // buf[ct&1] ready; prev reads done
        const int p = ct & 1;
        if (ct + 1 < 64) PWRITE((ct + 1) & 1);
        if (ct + 2 < 64) PLOAD(ct + 2);
        const float vn = vnorm32[ct * 16 + col];
        f32x4 a0 = {0.f, 0.f, 0.f, 0.f};
        f32x4 a1 = {0.f, 0.f, 0.f, 0.f};
        f32x4 a2 = {0.f, 0.f, 0.f, 0.f};
        #pragma unroll
        for (int kc = 0; kc < 8; ++kc) {
            s16x8 Bh = *(const s16x8*)&sbh[p][col][g * 8 + kc * 32];
            s16x8 Bl = *(const s16x8*)&sbl[p][col][g * 8 + kc * 32];
            a0 = __builtin_amdgcn_mfma_f32_16x16x32_bf16(ah[kc], Bh, a0, 0, 0, 0);
            a1 = __builtin_amdgcn_mfma_f32_16x16x32_bf16(al[kc], Bh, a1, 0, 0, 0);
            a2 = __builtin_amdgcn_mfma_f32_16x16x32_bf16(ah[kc], Bl, a2, 0, 0, 0);
        }
        #pragma unroll
        for (int r = 0; r < 4; ++r) {
            float sc = vn - 2.f * (a0[r] + a1[r] + a2[r]);
            int c = ct * 16 + col;
            if (sc < b1[r]) { b3[r] = b2[r]; b2[r] = b1[r]; i2[r] = i1[r]; b1[r] = sc; i1[r] = c; }
            else if (sc < b2[r]) { b3[r] = b2[r]; b2[r] = sc; i2[r] = c; }
            else b3[r] = fminf(b3[r], sc);
        }
    }
#undef PLOAD
#undef PWRITE

    // cross-lane top-3 merge over the 16 lanes of each token group
    #pragma unroll
    for (int off = 1; off < 16; off <<= 1) {
        #pragma unroll
        for (int r = 0; r < 4; ++r) {
            float c1 = __shfl_xor(b1[r], off, 64);
            int   j1 = __shfl_xor(i1[r], off, 64);
            float c2 = __shfl_xor(b2[r], off, 64);
            int   j2 = __shfl_xor(i2[r], off, 64);
            float c3 = __shfl_xor(b3[r], off, 64);
            float nb1, nb2, nb3; int ni1, ni2;
            if (c1 < b1[r] || (c1 == b1[r] && j1 < i1[r])) {
                nb1 = c1; ni1 = j1;
                if (b1[r] < c2 || (b1[r] == c2 && i1[r] < j2)) {
                    nb2 = b1[r]; ni2 = i1[r]; nb3 = fminf(b2[r], c2);
                } else {
                    nb2 = c2; ni2 = j2; nb3 = fminf(b1[r], c3);
                }
            } else {
                nb1 = b1[r]; ni1 = i1[r];
                if (c1 < b2[r] || (c1 == b2[r] && j1 < i2[r])) {
                    nb2 = c1; ni2 = j1; nb3 = fminf(b2[r], c2);
                } else {
                    nb2 = b2[r]; ni2 = i2[r]; nb3 = fminf(c1, b3[r]);
                }
            }
            b1[r] = nb1; b2[r] = nb2; b3[r] = nb3; i1[r] = ni1; i2[r] = ni2;
        }
    }
    if (col == 0) {
        double lsum = 0.0;
        #pragma unroll
        for (int r = 0; r < 4; ++r) {
            int m = mw + g * 4 + r;
            idx[m] = i1[r];
            if (stage0) idx_sum[m] = i1[r];
            else        idx_sum[m] += i1[r] * cumprod;
            mind[m] = b1[r];                 // score-only part
            lsum += (double)b1[r];
            if (b2[r] - b1[r] < DELTA) {
                int slot = atomicAdd(cnt, 1);
                int full = (b3[r] - b1[r] < DELTA) ? 1 : 0;
                flagged[slot] = (m << 1) | full;
                cand2[m] = i2[r];
            }
        }
        loss_s[w * 4 + g] = lsum;
    }
    __syncthreads();
    if (tid == 0) {
        double s = 0.0;
        #pragma unroll
        for (int q = 0; q < 16; ++q) s += loss_s[q];
        atomicAdd(loss_acc, s);
    }
}

// ---------------- exact fp64 rescan, batched 8 tokens/block, thread-per-e zi64 ----------------
__global__ __launch_bounds__(256) void rescan_k(const float* __restrict__ z,
                                                const float* __restrict__ zqv,
                                                const float* __restrict__ WinT,
                                                const float* __restrict__ cb,
                                                const double* __restrict__ vnorm64,
                                                const int* __restrict__ flagged,
                                                const int* __restrict__ cnt,
                                                const int* __restrict__ cand2,
                                                int* __restrict__ idx,
                                                int* __restrict__ idx_sum,
                                                float* __restrict__ mind,
                                                double* __restrict__ loss_acc,
                                                int cumprod, int stage0) {
    __shared__ double r64[8][CIN];           // 32 KB; first 16 KB reused as zi64[8][256]
    __shared__ int mArr[8], fArr[8], cAArr[8], cBArr[8];
    __shared__ double sredS[4];
    __shared__ int iredS[4];
    double* zi_l = &r64[0][0];               // alias (used after sync)
    const int tid = threadIdx.x;
    const int w = tid >> 6, l = tid & 63;
    const int n = *cnt;

    for (int jb = blockIdx.x; jb * 8 < n; jb += gridDim.x) {
        const int nt = min(8, n - jb * 8);
        __syncthreads();                     // protect LDS reuse across jb
        if (tid < nt) {
            int fm = flagged[jb * 8 + tid];
            int m = fm >> 1;
            mArr[tid] = m; fArr[tid] = fm & 1;
            cAArr[tid] = idx[m]; cBArr[tid] = cand2[m];
        }
        __syncthreads();
        // stage residuals (coalesced): thread covers k = tid, tid+256
        for (int t = 0; t < nt; ++t) {
            const int m = mArr[t];
            #pragma unroll
            for (int h = 0; h < 2; ++h) {
                int k = tid + h * 256;
                float rv = z[(size_t)m * CIN + k];
                if (!stage0) rv -= zqv[(size_t)m * CIN + k];   // fp32 subtract (matches ref)
                r64[t][k] = (double)rv;
            }
        }
        __syncthreads();
        // zi64: thread e = tid computes 8 dots; WinT rows read coalesced, r64 broadcast
        double acc[8] = {0, 0, 0, 0, 0, 0, 0, 0};
        #pragma unroll 4
        for (int k = 0; k < CIN; ++k) {
            double wv = (double)WinT[(size_t)k * EMB + tid];
            #pragma unroll
            for (int t = 0; t < 8; ++t) acc[t] += r64[t][k] * wv;
        }
        __syncthreads();
        #pragma unroll
        for (int t = 0; t < 8; ++t) zi_l[t * 256 + tid] = acc[t];
        __syncthreads();

        // pair-mode tokens: wave w handles t = w, w+4
        for (int t = w; t < nt; t += 4) {
            if (fArr[t]) continue;
            const int cA = cAArr[t], cB = cBArr[t], m = mArr[t];
            const double* zt = zi_l + t * 256;
            float4 vA = *(const float4*)(cb + (size_t)cA * EMB + 4 * l);
            float4 vB = *(const float4*)(cb + (size_t)cB * EMB + 4 * l);
            double z0 = zt[4 * l], z1 = zt[4 * l + 1];
            double z2 = zt[4 * l + 2], z3 = zt[4 * l + 3];
            double sA = z0 * (double)vA.x + z1 * (double)vA.y
                      + z2 * (double)vA.z + z3 * (double)vA.w;
            double sB = z0 * (double)vB.x + z1 * (double)vB.y
                      + z2 * (double)vB.z + z3 * (double)vB.w;
            #pragma unroll
            for (int off = 1; off < 64; off <<= 1) {
                sA += __shfl_xor(sA, off, 64);
                sB += __shfl_xor(sB, off, 64);
            }
            if (l == 0) {
                double dA = vnorm64[cA] - 2.0 * sA;
                double dB = vnorm64[cB] - 2.0 * sB;
                int bi; double best;
                if (dB < dA || (dB == dA && cB < cA)) { bi = cB; best = dB; }
                else                                   { bi = cA; best = dA; }
                int oldI = idx[m];
                if (bi != oldI) { idx[m] = bi; idx_sum[m] += (bi - oldI) * cumprod; }
                atomicAdd(loss_acc, best - (double)mind[m]);
                mind[m] = (float)best;
            }
        }

        // full-scan tokens: whole block, lane-per-code (fArr is block-uniform per t)
        for (int t = 0; t < nt; ++t) {
            if (!fArr[t]) continue;
            const int m = mArr[t];
            const double* zt = zi_l + t * 256;
            double bs = 1e300; int bc = 0;
            #pragma unroll
            for (int r = 0; r < 4; ++r) {
                const int c = (w << 8) + (r << 6) + l;
                const float* row = cb + (size_t)c * EMB;
                double s0 = 0, s1 = 0, s2 = 0, s3 = 0;
                for (int e = 0; e < EMB; e += 4) {
                    s0 += zt[e]     * (double)row[e];
                    s1 += zt[e + 1] * (double)row[e + 1];
                    s2 += zt[e + 2] * (double)row[e + 2];
                    s3 += zt[e + 3] * (double)row[e + 3];
                }
                double sc = vnorm64[c] - 2.0 * ((s0 + s1) + (s2 + s3));
                if (sc < bs) { bs = sc; bc = c; }       // ascending c within lane
            }
            #pragma unroll
            for (int off = 1; off < 64; off <<= 1) {
                double ob = __shfl_xor(bs, off, 64);
                int    oc = __shfl_xor(bc, off, 64);
                if (ob < bs || (ob == bs && oc < bc)) { bs = ob; bc = oc; }
            }
            if (l == 0) { sredS[w] = bs; iredS[w] = bc; }
            __syncthreads();
            if (tid == 0) {
                double best = sredS[0]; int bi = iredS[0];
                for (int q = 1; q < 4; ++q)
                    if (sredS[q] < best || (sredS[q] == best && iredS[q] < bi)) {
                        best = sredS[q]; bi = iredS[q];
                    }
                int oldI = idx[m];
                if (bi != oldI) { idx[m] = bi; idx_sum[m] += (bi - oldI) * cumprod; }
                atomicAdd(loss_acc, best - (double)mind[m]);
                mind[m] = (float)best;
            }
            __syncthreads();
        }
    }
}

// ---------------- zq (+)= T[idx]  (row gather); last stage also sums (z - zq)^2 ----------------
__global__ __launch_bounds__(256) void gather_k(const float* __restrict__ T,
                                                const int* __restrict__ idx,
                                                const float* __restrict__ z,
                                                float* __restrict__ zq,
                                                int stage0, int last,
                                                double* __restrict__ loss_acc) {
    __shared__ double red[256];
    int m = blockIdx.x * 16 + (threadIdx.x >> 4);
    int q = threadIdx.x & 15;
    const float* src = T + (size_t)idx[m] * CIN;
    float* dst = zq + (size_t)m * CIN;
    double s = 0.0;
    #pragma unroll
    for (int it = 0; it < 8; ++it) {
        int off = it * 64 + q * 4;
        float4 t = *reinterpret_cast<const float4*>(src + off);
        if (!stage0) {
            float4 o = *reinterpret_cast<const float4*>(dst + off);
            t.x += o.x; t.y += o.y; t.z += o.z; t.w += o.w;
        }
        *reinterpret_cast<float4*>(dst + off) = t;
        if (last) {
            float4 zv = *reinterpret_cast<const float4*>(z + (size_t)m * CIN + off);
            double d0 = (double)zv.x - (double)t.x;
            double d1 = (double)zv.y - (double)t.y;
            double d2 = (double)zv.z - (double)t.z;
            double d3 = (double)zv.w - (double)t.w;
            s += d0 * d0 + d1 * d1 + d2 * d2 + d3 * d3;
        }
    }
    if (last) {
        red[threadIdx.x] = s;
        __syncthreads();
        for (int off = 128; off > 0; off >>= 1) {
            if (threadIdx.x < off) red[threadIdx.x] += red[threadIdx.x + off];
            __syncthreads();
        }
        if (threadIdx.x == 0) atomicAdd(loss_acc + 1, red[0]);
    }
}

// ---------------- finalize ----------------
__global__ void final_k(const int* __restrict__ idx_sum,
                        const double* __restrict__ loss_acc,
                        float* __restrict__ out) {
    int i = blockIdx.x * blockDim.x + threadIdx.x;
    if (i < MTOK) out[MTOK * CIN + i] = (float)idx_sum[i];
    if (i == 0) {
        double loss = 2.0 * loss_acc[0] / (3.0 * (double)MTOK * (double)EMB)
                    + loss_acc[1] / ((double)MTOK * (double)CIN);
        out[MTOK * CIN + MTOK] = (float)loss;
    }
}

extern "C" void kernel_launch(void* const* d_in, const int* in_sizes, int n_in,
                              void* d_out, int out_size, void* d_ws, size_t ws_size,
                              hipStream_t stream) {
    const float* z     = (const float*)d_in[0];
    const float* W_in  = (const float*)d_in[1];
    const float* W_out = (const float*)d_in[2];
    const float* cbs   = (const float*)d_in[3];
    float* out = (float*)d_out;
    char* ws = (char*)d_ws;

    // ws layout (16B-aligned)
    double* vnorm64  = (double*)ws;                               // 24576
    double* loss_acc = (double*)(ws + 24576);                     // 16
    float*  vnorm32  = (float*)(ws + 24592);                      // 12288
    int*    cnt      = (int*)(ws + 36880);                        // 16
    u16*    cbh      = (u16*)(ws + 36896);                        // 1572864
    u16*    cbl      = (u16*)(ws + 1609760);                      // 1572864
    u16*    wh       = (u16*)(ws + 3182624);                      // 786432
    u16*    wl       = (u16*)(ws + 3969056);                      // 786432
    float*  WinT     = (float*)(ws + 4755488);                    // 1572864
    float*  T        = (float*)(ws + 6328352);                    // 6291456
    float*  zi       = (float*)(ws + 12619808);                   // 33554432
    char*   p        = ws + 12619808 + (size_t)MTOK * EMB * 4;
    int*    idx      = (int*)p;                                   // 131072
    int*    idx_sum  = (int*)(p + 131072);                        // 131072
    int*    flagged  = (int*)(p + 262144);                        // 131072
    float*  mind     = (float*)(p + 393216);                      // 131072
    int*    cand2    = (int*)(p + 524288);                        // 131072

    float* zq = out;  // z_q lives in d_out[0 .. MTOK*CIN)

    init_k<<<dim3(1), dim3(1), 0, stream>>>(loss_acc, cnt);
    prep_cb_k<<<dim3(VQ * NCODE), dim3(64), 0, stream>>>(cbs, vnorm64, vnorm32, cbh, cbl);
    prep_w_k<<<dim3(VQ * EMB * CIN / 256), dim3(256), 0, stream>>>(W_in, wh, wl);
    prep_wt_k<<<dim3(VQ * EMB * CIN / 256), dim3(256), 0, stream>>>(W_in, WinT);
    prep_T_k<<<dim3(NCODE / 64, CIN / 64, VQ), dim3(256), 0, stream>>>(cbs, W_out, T);

    const int cumprod[VQ] = {1, 1024, 1024 * 1024};
    for (int i = 0; i < VQ; ++i) {
        const float* cb = cbs + (size_t)i * NCODE * EMB;
        zi_mfma_k<<<dim3(MTOK / 64), dim3(256), 0, stream>>>(
            z, zq, wh + (size_t)i * EMB * CIN, wl + (size_t)i * EMB * CIN,
            zi, loss_acc, i == 0 ? 1 : 0);
        pref_k<<<dim3(MTOK / 64), dim3(256), 0, stream>>>(
            zi, cbh + (size_t)i * NCODE * EMB, cbl + (size_t)i * NCODE * EMB,
            vnorm32 + i * NCODE, idx, idx_sum, mind, flagged, cnt + i, cand2,
            loss_acc, i == 0 ? 1 : 0, cumprod[i]);
        rescan_k<<<dim3(256), dim3(256), 0, stream>>>(
            z, zq, WinT + (size_t)i * EMB * CIN, cb, vnorm64 + i * NCODE,
            flagged, cnt + i, cand2, idx, idx_sum, mind, loss_acc, cumprod[i],
            i == 0 ? 1 : 0);
        gather_k<<<dim3(MTOK / 16), dim3(256), 0, stream>>>(
            T + (size_t)i * NCODE * CIN, idx, z, zq, i == 0 ? 1 : 0,
            i == VQ - 1 ? 1 : 0, loss_acc);
    }
    final_k<<<dim3(MTOK / 256), dim3(256), 0, stream>>>(idx_sum, loss_acc, out);
}